// Round 10
// baseline (94.654 us; speedup 1.0000x reference)
//
#include <hip/hip_runtime.h>

// Problem constants
#define TT     2048
#define NB     32
#define NL     10
#define NU     64
#define TTILE  64
#define TPB    4           // time-tiles per block (serial)
#define NG     8           // tile-groups = chunks per b after in-block fold
#define NW     20          // iterated-sum words per (b,chunk,u)
#define DT3    145         // d-tile row stride (cols 144 = l=1..9 x 16; odd)

// LDS float offsets -- B is 20 regs x 64 lanes x 8 bf16 = 10240 shorts = 5120 FLOATS
// (R9 bug: allotted 2560). dtile aliases the A region (A rebuilt each tile).
#define B_OFF    0         // [5120]  B frags, persistent across tile loop
#define A_OFF    5120      // [2048]  A frags (8 regs x 64 x 8 bf16), per tile
#define D_OFF    5120      // dtile aliases A onward: 65 rows x 145 = 9425 floats
#define W0_OFF   14548     // [32]    word-0 endpoints
#define SM_FLOATS 14580    // 58,320 B -> 2 blocks/CU

typedef __attribute__((ext_vector_type(8))) short short8v;   // 8 bf16
typedef __attribute__((ext_vector_type(4))) float float4v;   // MFMA C/D

__device__ inline short f2bf(float f) {   // RNE float->bf16 raw bits
    unsigned u = __float_as_uint(f);
    u += 0x7fffu + ((u >> 16) & 1u);
    return (short)(u >> 16);
}

// ---- Chen composition (full 20-word alphabet), C = A(earlier) ∘ B(later) ----
// 0:(0) | 1:(1) 2:(2) 3:(12) | 4:(3) 5:(4) 6:(5) 7:(34) 8:(45) 9:(345)
// 10:(6) 11:(7) 12:(8) 13:(9) 14:(67) 15:(78) 16:(89) 17:(678) 18:(789) 19:(6789)
__device__ inline void chen_combine(const float* A, const float* B, float* C) {
    C[0]  = A[0] + B[0];
    C[1]  = A[1] + B[1];
    C[2]  = A[2] + B[2];
    C[3]  = A[3] + A[1]*B[2] + B[3];
    C[4]  = A[4] + B[4];
    C[5]  = A[5] + B[5];
    C[6]  = A[6] + B[6];
    C[7]  = A[7] + A[4]*B[5] + B[7];
    C[8]  = A[8] + A[5]*B[6] + B[8];
    C[9]  = A[9] + A[7]*B[6] + A[4]*B[8] + B[9];
    C[10] = A[10] + B[10];
    C[11] = A[11] + B[11];
    C[12] = A[12] + B[12];
    C[13] = A[13] + B[13];
    C[14] = A[14] + A[10]*B[11] + B[14];
    C[15] = A[15] + A[11]*B[12] + B[15];
    C[16] = A[16] + A[12]*B[13] + B[16];
    C[17] = A[17] + A[14]*B[12] + A[10]*B[15] + B[17];
    C[18] = A[18] + A[15]*B[13] + A[11]*B[16] + B[18];
    C[19] = A[19] + A[17]*B[13] + A[14]*B[16] + A[10]*B[18] + B[19];
}

// ---- chain-local Chen combiners ----
struct Chen1 {  // S0=(1) S1=(2) S2=(12)
    __device__ void operator()(const float* A, const float* B, float* C) const {
        C[2] = A[2] + A[0]*B[1] + B[2];
        C[0] = A[0] + B[0];  C[1] = A[1] + B[1];
    }
};
struct Chen2 {  // S0=(3) S1=(4) S2=(5) S3=(34) S4=(45) S5=(345)
    __device__ void operator()(const float* A, const float* B, float* C) const {
        C[5] = A[5] + A[3]*B[2] + A[0]*B[4] + B[5];
        C[3] = A[3] + A[0]*B[1] + B[3];
        C[4] = A[4] + A[1]*B[2] + B[4];
        C[0] = A[0] + B[0];  C[1] = A[1] + B[1];  C[2] = A[2] + B[2];
    }
};
struct Chen3 {  // S0..3=(6)(7)(8)(9) S4=(67) S5=(78) S6=(89) S7=(678) S8=(789) S9=(6789)
    __device__ void operator()(const float* A, const float* B, float* C) const {
        C[9] = A[9] + A[7]*B[3] + A[4]*B[6] + A[0]*B[8] + B[9];
        C[7] = A[7] + A[4]*B[2] + A[0]*B[5] + B[7];
        C[8] = A[8] + A[5]*B[3] + A[1]*B[6] + B[8];
        C[4] = A[4] + A[0]*B[1] + B[4];
        C[5] = A[5] + A[1]*B[2] + B[5];
        C[6] = A[6] + A[2]*B[3] + B[6];
        C[0] = A[0] + B[0];  C[1] = A[1] + B[1];
        C[2] = A[2] + B[2];  C[3] = A[3] + B[3];
    }
};

// Cross-lane fold of 4 t-ordered groups (grp = lane>>4) via xor-16/32 tree.
// After return every lane holds the full combined value.
template <int N, typename CH>
__device__ inline void wave_fold(float* S, int grp, CH chen) {
    float O[N], A[N], Bv[N], C[N];
#pragma unroll
    for (int w = 0; w < N; ++w) O[w] = __shfl_xor(S[w], 16);
    {
        const bool e = (grp & 1) == 0;
#pragma unroll
        for (int w = 0; w < N; ++w) { A[w] = e ? S[w] : O[w]; Bv[w] = e ? O[w] : S[w]; }
        chen(A, Bv, C);
    }
#pragma unroll
    for (int w = 0; w < N; ++w) O[w] = __shfl_xor(C[w], 32);
    {
        const bool e = (grp & 2) == 0;
#pragma unroll
        for (int w = 0; w < N; ++w) { A[w] = e ? C[w] : O[w]; Bv[w] = e ? O[w] : C[w]; }
        chen(A, Bv, S);
    }
}

// Fused kernel: B frags once; loop over 4 time-tiles {A frags -> MFMA M = X*K
// (wave 3 adds boundary row) -> scatter -> scan on d = M[t]-M[t-1] -> wave_fold};
// accumulate the 4 chunk states in registers via chain-local Chen; write 20
// words once per block.
__global__ __launch_bounds__(256, 2)
void k_fused(const float* __restrict__ x, const float* __restrict__ K,
             float* __restrict__ L) {
    __shared__ __align__(16) float sm[SM_FLOATS];
    short* B_lds = (short*)(sm + B_OFF);   // [20][64][8] bf16, persistent
    short* A_lds = (short*)(sm + A_OFF);   // [8][64][8] bf16, per tile
    float* dtile = sm + D_OFF;             // [r*145 + (l-1)*16 + su], aliases A
    float* w0buf = sm + W0_OFF;            // [32]

    const int tid = threadIdx.x;
    const int tg  = blockIdx.x;    // 0..7  tile group (tiles 4tg..4tg+3)
    const int uq  = blockIdx.y;    // 0..3
    const int b   = blockIdx.z;    // 0..31
    const int uh  = uq * 16;
    const int wv  = tid >> 6, lane = tid & 63;
    const int sub = (tid >> 4) & 3;
    const int su  = tid & 15;
    const int qd  = lane >> 4, nl = lane & 15;
    const float dtc = 2.0f / (float)(TT - 1);

    // ---- B fragments (once): strided K loads -> one short8v write each ----
    // reg = l*2+s; element j of (reg,ln) = K[f = s*32+(ln>>4)*8+j][l][uh+(ln&15)]
#pragma unroll
    for (int i = 0; i < 5; ++i) {
        const int idx = i * 256 + tid;
        const int ln = idx & 63, r20 = idx >> 6;
        const int l = r20 >> 1, s = r20 & 1;
        const int f0 = s * 32 + (ln >> 4) * 8;
        const int u = uh + (ln & 15);
        const float* kp = K + (size_t)f0 * (NL * NU) + l * NU + u;
        short8v v;
#pragma unroll
        for (int j = 0; j < 8; ++j) v[j] = f2bf(kp[(size_t)j * (NL * NU)]);
        *(short8v*)(B_lds + (size_t)idx * 8) = v;
    }

    // per-wave chain accumulators (identity = zeros; chen(0,S)=S)
    float E[10];
#pragma unroll
    for (int i = 0; i < 10; ++i) E[i] = 0.0f;
    float E0 = 0.0f;   // word (0), wave 3

#pragma unroll 1
    for (int c = 0; c < TPB; ++c) {
        const int tt = tg * TPB + c;       // global tile 0..31
        const int t0 = tt * TTILE;

        // ---- A fragments: bf16(X rows) straight from global ----
#pragma unroll
        for (int i = 0; i < 2; ++i) {
            const int e = i * 256 + tid;            // 0..511
            const int le = e & 63, reg = e >> 6;    // reg = w*2+s
            const int w = reg >> 1, s = reg & 1;
            const int t = w * 16 + (le & 15);
            const int f0 = s * 32 + (le >> 4) * 8;
            const int tg2 = t0 + t;
            const float* xp = x + (size_t)(b * TT + tg2) * 63;
            const float tv = (float)tg2 * dtc - 1.0f;
            short8v v;
#pragma unroll
            for (int j = 0; j < 8; ++j) {
                const int f = f0 + j;
                v[j] = f2bf(f < 63 ? xp[f] : tv);
            }
            *(short8v*)(A_lds + (size_t)e * 8) = v;
        }

        // ---- boundary A-fragment (wave 3): row 0 = X[max(t0-1,0)], rest 0 ----
        short8v ab0 = {0,0,0,0,0,0,0,0}, ab1 = {0,0,0,0,0,0,0,0};
        if (wv == 3 && su == 0) {
            const int tp = (tt > 0) ? t0 - 1 : 0;
            const float* xp = x + (size_t)(b * TT + tp) * 63;
            const float tv = (float)tp * dtc - 1.0f;
#pragma unroll
            for (int j = 0; j < 8; ++j) {
                const int fa = qd * 8 + j;           // s=0 half (f<32, valid)
                const int fb = 32 + qd * 8 + j;      // s=1 half
                ab0[j] = f2bf(xp[fa]);
                ab1[j] = f2bf(fb < 63 ? xp[fb] : tv);
            }
        }
        __syncthreads();   // A visible (and B on c=0); prior scan reads done

        // ---- MFMA: wave wv computes M rows [16wv,16wv+16) x 160 cols ----
        const short8v* A8 = (const short8v*)A_lds;
        const short8v* B8 = (const short8v*)B_lds;
        const short8v a0 = A8[(wv * 2 + 0) * 64 + lane];
        const short8v a1 = A8[(wv * 2 + 1) * 64 + lane];
        float4v acc[10];
        float bnd[10];
#pragma unroll
        for (int nt = 0; nt < 10; ++nt) {
            const short8v b0 = B8[(nt * 2 + 0) * 64 + lane];
            const short8v b1 = B8[(nt * 2 + 1) * 64 + lane];
            float4v z = {0.f, 0.f, 0.f, 0.f};
            z = __builtin_amdgcn_mfma_f32_16x16x32_bf16(a0, b0, z, 0, 0, 0);
            z = __builtin_amdgcn_mfma_f32_16x16x32_bf16(a1, b1, z, 0, 0, 0);
            acc[nt] = z;
            if (wv == 3) {   // boundary row: only C row 0 (reg 0, lanes 0-15) used
                float4v zb = {0.f, 0.f, 0.f, 0.f};
                zb = __builtin_amdgcn_mfma_f32_16x16x32_bf16(ab0, b0, zb, 0, 0, 0);
                zb = __builtin_amdgcn_mfma_f32_16x16x32_bf16(ab1, b1, zb, 0, 0, 0);
                bnd[nt] = zb[0];
            }
        }
        __syncthreads();   // A/B frag reads done; dtile (aliasing A) writable

        // ---- scatter M -> dtile rows 1..64; wave 3: row 0 + word-0 endpoints ----
#pragma unroll
        for (int nt = 1; nt < 10; ++nt)
#pragma unroll
            for (int r = 0; r < 4; ++r)
                dtile[(wv * 16 + qd * 4 + r + 1) * DT3 + (nt - 1) * 16 + nl] = acc[nt][r];
        if (wv == 3) {
            if (qd == 0) {           // lanes 0-15: boundary row (dtile row 0)
#pragma unroll
                for (int nt = 1; nt < 10; ++nt)
                    dtile[(nt - 1) * 16 + nl] = bnd[nt];
                w0buf[nl] = bnd[0];                  // M[t0-1][0][u]
            }
            if (lane >= 48)          // C row 63 = qd 3, reg 3
                w0buf[16 + (lane - 48)] = acc[0][3]; // M[t0+63][0][u]
        }
        __syncthreads();

        // ---- scan: wave = chain; lanes = 4 sub-chunks x 16 u; d = M[t]-M[t-1] ----
        const float* dp = dtile + su;
        const int tb = sub * 16;
        float S[10];
#pragma unroll
        for (int i = 0; i < 10; ++i) S[i] = 0.0f;

        if (wv == 0) {            // chain 1: l=1,2 -> col offs 0,16
            float m1 = dp[tb * DT3 + 0], m2 = dp[tb * DT3 + 16];
            for (int r = tb + 1; r <= tb + 16; ++r) {
                const float n1 = dp[r * DT3 + 0];
                const float n2 = dp[r * DT3 + 16];
                const float d1 = n1 - m1, d2 = n2 - m2;
                m1 = n1;  m2 = n2;
                S[2] += S[0] * d2;
                S[0] += d1;  S[1] += d2;
            }
            wave_fold<3>(S, sub, Chen1());
            float Cw[3];
            Chen1()(E, S, Cw);
#pragma unroll
            for (int w = 0; w < 3; ++w) E[w] = Cw[w];
        } else if (wv == 1) {     // chain 2: l=3,4,5 -> 32,48,64
            float m3 = dp[tb * DT3 + 32], m4 = dp[tb * DT3 + 48], m5 = dp[tb * DT3 + 64];
            for (int r = tb + 1; r <= tb + 16; ++r) {
                const float n3 = dp[r * DT3 + 32];
                const float n4 = dp[r * DT3 + 48];
                const float n5 = dp[r * DT3 + 64];
                const float d3 = n3 - m3, d4 = n4 - m4, d5 = n5 - m5;
                m3 = n3;  m4 = n4;  m5 = n5;
                S[5] += S[3] * d5;
                S[3] += S[0] * d4;
                S[4] += S[1] * d5;
                S[0] += d3;  S[1] += d4;  S[2] += d5;
            }
            wave_fold<6>(S, sub, Chen2());
            float Cw[6];
            Chen2()(E, S, Cw);
#pragma unroll
            for (int w = 0; w < 6; ++w) E[w] = Cw[w];
        } else if (wv == 2) {     // chain 3: l=6..9 -> 80,96,112,128
            float m6 = dp[tb * DT3 + 80],  m7 = dp[tb * DT3 + 96];
            float m8 = dp[tb * DT3 + 112], m9 = dp[tb * DT3 + 128];
            for (int r = tb + 1; r <= tb + 16; ++r) {
                const float n6 = dp[r * DT3 + 80];
                const float n7 = dp[r * DT3 + 96];
                const float n8 = dp[r * DT3 + 112];
                const float n9 = dp[r * DT3 + 128];
                const float d6 = n6 - m6, d7 = n7 - m7, d8 = n8 - m8, d9 = n9 - m9;
                m6 = n6;  m7 = n7;  m8 = n8;  m9 = n9;
                S[9] += S[7] * d9;
                S[7] += S[4] * d8;
                S[8] += S[5] * d9;
                S[4] += S[0] * d7;
                S[5] += S[1] * d8;
                S[6] += S[2] * d9;
                S[0] += d6;  S[1] += d7;  S[2] += d8;  S[3] += d9;
            }
            wave_fold<10>(S, sub, Chen3());
            float Cw[10];
            Chen3()(E, S, Cw);
#pragma unroll
            for (int w = 0; w < 10; ++w) E[w] = Cw[w];
        } else {                  // wave 3: word (0) telescopes
            E0 += w0buf[16 + nl] - w0buf[nl];
        }
        __syncthreads();   // scan reads done; next iteration may overwrite LDS
    }

    // ---- write the 20 words for (b, chunk tg, uq) ----
    float* Lb = L + ((size_t)(b * NG + tg) * NW) * NU + uh + su;
    if (sub == 0) {
        if (wv == 0) {
            Lb[1*NU] = E[0];  Lb[2*NU] = E[1];  Lb[3*NU] = E[2];
        } else if (wv == 1) {
            Lb[4*NU] = E[0];  Lb[5*NU] = E[1];  Lb[6*NU] = E[2];
            Lb[7*NU] = E[3];  Lb[8*NU] = E[4];  Lb[9*NU] = E[5];
        } else if (wv == 2) {
            Lb[10*NU] = E[0]; Lb[11*NU] = E[1]; Lb[12*NU] = E[2]; Lb[13*NU] = E[3];
            Lb[14*NU] = E[4]; Lb[15*NU] = E[5]; Lb[16*NU] = E[6];
            Lb[17*NU] = E[7]; Lb[18*NU] = E[8]; Lb[19*NU] = E[9];
        } else {
            Lb[0] = E0;
        }
    }
}

// Kernel 2: fold 8 chunks per b. 4 waves x 2 serial chunks + 2-level LDS tree.
__global__ __launch_bounds__(256)
void k_fold(const float* __restrict__ L, float* __restrict__ out) {
    __shared__ float buf[2][NW][NU];    // 10,240 B
    const int b = blockIdx.x;
    const int u = threadIdx.x & 63;
    const int q = threadIdx.x >> 6;     // 0..3
    const float* Lb = L + (size_t)b * NG * NW * NU + u;

    float E[NW], Bw[NW], Cw[NW];
    {
        const float* p = Lb + (size_t)(q * 2) * NW * NU;
#pragma unroll
        for (int w = 0; w < NW; ++w) E[w] = p[w * NU];
    }
    {
        const float* p = Lb + (size_t)(q * 2 + 1) * NW * NU;
#pragma unroll
        for (int w = 0; w < NW; ++w) Bw[w] = p[w * NU];
        chen_combine(E, Bw, Cw);
#pragma unroll
        for (int w = 0; w < NW; ++w) E[w] = Cw[w];
    }

    if (q & 1) {                        // q=1 -> buf[0], q=3 -> buf[1]
#pragma unroll
        for (int w = 0; w < NW; ++w) buf[(q - 1) >> 1][w][u] = E[w];
    }
    __syncthreads();
    if (!(q & 1)) {                     // q=0 <- buf[0], q=2 <- buf[1]
#pragma unroll
        for (int w = 0; w < NW; ++w) Bw[w] = buf[q >> 1][w][u];
        chen_combine(E, Bw, Cw);
#pragma unroll
        for (int w = 0; w < NW; ++w) E[w] = Cw[w];
    }
    __syncthreads();
    if (q == 2) {
#pragma unroll
        for (int w = 0; w < NW; ++w) buf[0][w][u] = E[w];
    }
    __syncthreads();
    if (q == 0) {
#pragma unroll
        for (int w = 0; w < NW; ++w) Bw[w] = buf[0][w][u];
        chen_combine(E, Bw, Cw);
        out[b * NU + u] = Cw[0] + Cw[3] + Cw[9] + Cw[19];
    }
}

extern "C" void kernel_launch(void* const* d_in, const int* in_sizes, int n_in,
                              void* d_out, int out_size, void* d_ws, size_t ws_size,
                              hipStream_t stream) {
    const float* x = (const float*)d_in[0];   // (32, 2048, 63) fp32
    const float* K = (const float*)d_in[1];   // (64, 10, 64)  fp32
    float* out = (float*)d_out;               // (32, 64) fp32
    float* L   = (float*)d_ws;                // 1,310,720 B

    dim3 g1(NG, 4, NB);                       // (8, 4, 32) = 1024 blocks
    k_fused<<<g1, 256, 0, stream>>>(x, K, L);
    k_fold<<<NB, 256, 0, stream>>>(L, out);
}